// Round 4
// baseline (737.358 us; speedup 1.0000x reference)
//
#include <hip/hip_runtime.h>
#include <cstdint>

typedef uint16_t u16;
typedef unsigned long long u64;
typedef __attribute__((ext_vector_type(8))) short bf16x8;
typedef __attribute__((ext_vector_type(4))) float f32x4;

#define EPSBN 1e-5f

__device__ __forceinline__ float bf2f(u16 h) {
  return __uint_as_float(((unsigned)h) << 16);
}
__device__ __forceinline__ u16 f2bf(float f) {
  unsigned u = __float_as_uint(f);
  unsigned r = u + 0x7fffu + ((u >> 16) & 1u);
  return (u16)(r >> 16);
}
// order-preserving fp32 <-> uint32 map (for packed atomicMax argmax)
__device__ __forceinline__ unsigned monoEnc(float v) {
  unsigned b = __float_as_uint(v);
  return (b & 0x80000000u) ? ~b : (b | 0x80000000u);
}
__device__ __forceinline__ float monoDec(unsigned u) {
  unsigned b = (u & 0x80000000u) ? (u & 0x7fffffffu) : ~u;
  return __uint_as_float(b);
}

// ---------------------------------------------------------------------------
// K0: W5 -> bf16 hi/lo in FRAGMENT-LINEAR layout:
//   flat f: j=f&7, l15=(f>>3)&15, quad=(f>>7)&3, ks=(f>>9)&3, g=f>>11
//   holds W5[ch = g*16+l15][k = ks*32+quad*8+j]
//   => a wave (quad,l15 lanes) reads 1024 B contiguous per (g,ks).
// Also: transpose W2/W3/W4, copy W1, fold BN scale/shift for L1..L4 into Wf.
// Wf floats: Wt2@0(4096) Wt3@4096 Wt4@8192(8192) W1@16384(192)
//            scale@16576(320) shift@16896(320)
// ---------------------------------------------------------------------------
__global__ void k0_prep(const float* __restrict__ W5,
                        const float* __restrict__ W1, const float* __restrict__ W2,
                        const float* __restrict__ W3, const float* __restrict__ W4,
                        const float* g1, const float* b1, const float* m1, const float* v1,
                        const float* g2, const float* b2, const float* m2, const float* v2,
                        const float* g3, const float* b3, const float* m3, const float* v3,
                        const float* g4, const float* b4, const float* m4, const float* v4,
                        u16* __restrict__ W5h, u16* __restrict__ W5l,
                        float* __restrict__ Wf)
{
  int idx = blockIdx.x * 256 + threadIdx.x;
  if (idx < 131072) {
    int f = idx;
    int j = f & 7, l15 = (f >> 3) & 15, quad = (f >> 7) & 3, ks = (f >> 9) & 3, g = f >> 11;
    int ch = g * 16 + l15;
    int k  = ks * 32 + quad * 8 + j;
    float w = W5[ch * 128 + k];
    u16 hi = f2bf(w);
    W5h[f] = hi;
    W5l[f] = f2bf(w - bf2f(hi));
    return;
  }
  int j = idx - 131072;
  if (j < 4096) {                       // Wt2[j2*64+o] = W2[o*64+j2]
    Wf[j] = W2[(j & 63) * 64 + (j >> 6)];
  } else if (j < 8192) {
    int t = j - 4096;
    Wf[j] = W3[(t & 63) * 64 + (t >> 6)];
  } else if (j < 16384) {               // Wt4[j4*128+o] = W4[o*64+j4]
    int t = j - 8192;
    Wf[j] = W4[(t & 127) * 64 + (t >> 7)];
  } else if (j < 16576) {
    Wf[j] = W1[j - 16384];
  } else if (j < 16896) {
    int t = j - 16576;
    const float *g, *bb, *mm, *vv; int ch;
    if (t < 64)       { g = g1; bb = b1; mm = m1; vv = v1; ch = t;       }
    else if (t < 128) { g = g2; bb = b2; mm = m2; vv = v2; ch = t - 64;  }
    else if (t < 192) { g = g3; bb = b3; mm = m3; vv = v3; ch = t - 128; }
    else              { g = g4; bb = b4; mm = m4; vv = v4; ch = t - 192; }
    float s = g[ch] / sqrtf(vv[ch] + EPSBN);
    Wf[16576 + t] = s;
    Wf[16896 + t] = bb[ch] - mm[ch] * s;
  }
}

// ---------------------------------------------------------------------------
// K1: layers 1-4, one point per thread. hs[64][128] = exactly 32 KB (5
// blocks/CU); lane-major access is conflict-free without padding. Explicit
// next-j prefetch. L4 in 2 chunks of 64 outputs (VGPR cap). Output h4 split
// hi/lo bf16, layout [b][kg=ch/8][n][8] -> coalesced 16B stores.
// ---------------------------------------------------------------------------
__global__ __launch_bounds__(128, 2) void k1_conv(
    const float* __restrict__ x, const float* __restrict__ Wf,
    u16* __restrict__ H4a, u16* __restrict__ H4b)
{
  __shared__ float hs[64][128];
  const int tid = threadIdx.x;
  const int pid = blockIdx.x * 128 + tid;
  const int b = pid >> 13, n = pid & 8191;

  const float* __restrict__ Wt2 = Wf;
  const float* __restrict__ Wt3 = Wf + 4096;
  const float* __restrict__ Wt4 = Wf + 8192;
  const float* __restrict__ W1  = Wf + 16384;
  const float* __restrict__ SC  = Wf + 16576;
  const float* __restrict__ SH  = Wf + 16896;

  const float x0 = x[(b * 3 + 0) * 8192 + n];
  const float x1 = x[(b * 3 + 1) * 8192 + n];
  const float x2 = x[(b * 3 + 2) * 8192 + n];

  // L1 (3 -> 64)
  #pragma unroll
  for (int o = 0; o < 64; ++o) {
    float c = W1[o * 3] * x0;
    c = fmaf(W1[o * 3 + 1], x1, c);
    c = fmaf(W1[o * 3 + 2], x2, c);
    hs[o][tid] = fmaxf(0.f, fmaf(c, SC[o], SH[o]));
  }

  // L2 (64 -> 64)
  {
    float hn[64];
    #pragma unroll
    for (int o = 0; o < 64; ++o) hn[o] = 0.f;
    float hj = hs[0][tid];
    #pragma unroll 2
    for (int j = 0; j < 64; ++j) {
      float hjn = hs[(j + 1) & 63][tid];
      const float* __restrict__ wr = &Wt2[j * 64];
      #pragma unroll
      for (int o = 0; o < 64; ++o) hn[o] = fmaf(wr[o], hj, hn[o]);
      hj = hjn;
    }
    #pragma unroll
    for (int o = 0; o < 64; ++o)
      hs[o][tid] = fmaxf(0.f, fmaf(hn[o], SC[64 + o], SH[64 + o]));
  }

  // L3 (64 -> 64)
  {
    float hn[64];
    #pragma unroll
    for (int o = 0; o < 64; ++o) hn[o] = 0.f;
    float hj = hs[0][tid];
    #pragma unroll 2
    for (int j = 0; j < 64; ++j) {
      float hjn = hs[(j + 1) & 63][tid];
      const float* __restrict__ wr = &Wt3[j * 64];
      #pragma unroll
      for (int o = 0; o < 64; ++o) hn[o] = fmaf(wr[o], hj, hn[o]);
      hj = hjn;
    }
    #pragma unroll
    for (int o = 0; o < 64; ++o)
      hs[o][tid] = fmaxf(0.f, fmaf(hn[o], SC[128 + o], SH[128 + o]));
  }

  // L4 (64 -> 128) in 2 chunks of 64 outputs
  for (int half = 0; half < 2; ++half) {
    float hn[64];
    #pragma unroll
    for (int o = 0; o < 64; ++o) hn[o] = 0.f;
    float hj = hs[0][tid];
    #pragma unroll 2
    for (int j = 0; j < 64; ++j) {
      float hjn = hs[(j + 1) & 63][tid];
      const float* __restrict__ wr = &Wt4[j * 128 + half * 64];
      #pragma unroll
      for (int o = 0; o < 64; ++o) hn[o] = fmaf(wr[o], hj, hn[o]);
      hj = hjn;
    }
    #pragma unroll
    for (int o8 = 0; o8 < 8; ++o8) {
      int kg = half * 8 + o8;
      unsigned hv[4], lv[4];
      #pragma unroll
      for (int p = 0; p < 4; ++p) {
        int oc = o8 * 8 + 2 * p;
        float v0 = fmaxf(0.f, fmaf(hn[oc],     SC[192 + half * 64 + oc],     SH[192 + half * 64 + oc]));
        float v1 = fmaxf(0.f, fmaf(hn[oc + 1], SC[192 + half * 64 + oc + 1], SH[192 + half * 64 + oc + 1]));
        u16 a0 = f2bf(v0), a1 = f2bf(v1);
        float e0 = v0 - bf2f(a0), e1 = v1 - bf2f(a1);
        hv[p] = (unsigned)a0 | ((unsigned)a1 << 16);
        lv[p] = (unsigned)f2bf(e0) | ((unsigned)f2bf(e1) << 16);
      }
      uint4 ha, la;
      ha.x = hv[0]; ha.y = hv[1]; ha.z = hv[2]; ha.w = hv[3];
      la.x = lv[0]; la.y = lv[1]; la.z = lv[2]; la.w = lv[3];
      size_t e = ((size_t)(b * 16 + kg) * 8192 + n) * 8;
      *(uint4*)&H4a[e] = ha;
      *(uint4*)&H4b[e] = la;
    }
  }
}

// ---------------------------------------------------------------------------
// K2 v3: 64-pt tile per block. Ah/Al in LDS (32 KB, XOR-swizzled chunks ->
// conflict-free b128 reads AND staging writes). One __syncthreads total.
// 8 channel chunks of 128; wave = 32 ch x 64 pts (acc 4x2 f32x4).
// Exact product via Ah*Bh + Ah*Bl + Al*Bh (3 bf16 MFMA sweeps).
// Per-channel argmax: in-thread (strict >, ascending pt), quad-fold via
// __shfl_xor, then packed u64 atomicMax (value-mono<<32 | 8191-pt).
// ---------------------------------------------------------------------------
__global__ __launch_bounds__(256, 4) void k2_gemm(
    const u16* __restrict__ H4a, const u16* __restrict__ H4b,
    const u16* __restrict__ W5h, const u16* __restrict__ W5l,
    const int* __restrict__ sel, int P,
    u64* __restrict__ amax)
{
  __shared__ u16 Ah[64 * 128];
  __shared__ u16 Al[64 * 128];

  const int s = blockIdx.x;     // 64-pt tile
  const int b = blockIdx.y;
  const int tid = threadIdx.x;
  const int lane = tid & 63, wv = tid >> 6;
  const int l15 = lane & 15, quad = lane >> 4;
  const int mb = s << 6;

  // stage: iter i -> chunk c = i*4+wv (fixed per wave), rows p = lane.
  // global: wave reads 64 rows x 16B contiguous; LDS: chunk c^(p&7) => 8-way
  // spread over bank groups (optimal for b128 writes).
  #pragma unroll
  for (int i = 0; i < 4; ++i) {
    int c = i * 4 + wv;
    int p = lane;
    int pt = mb + p;
    uint4 va; va.x = va.y = va.z = va.w = 0u;
    uint4 vb; vb.x = vb.y = vb.z = vb.w = 0u;
    int n0 = pt;
    bool ok = true;
    if (sel) { ok = (pt < P); n0 = ok ? (sel[b * 600 + pt] & 8191) : 0; }
    if (ok) {
      size_t e = ((size_t)(b * 16 + c) * 8192 + n0) * 8;
      va = *(const uint4*)&H4a[e];
      vb = *(const uint4*)&H4b[e];
    }
    int off = p * 128 + ((c ^ (p & 7)) << 3);
    *(uint4*)&Ah[off] = va;
    *(uint4*)&Al[off] = vb;
  }
  __syncthreads();

  const f32x4 vzero = {0.f, 0.f, 0.f, 0.f};

  #pragma unroll 1
  for (int nc = 0; nc < 8; ++nc) {
    f32x4 acc[4][2];
    #pragma unroll
    for (int tm = 0; tm < 4; ++tm)
      #pragma unroll
      for (int tn = 0; tn < 2; ++tn)
        acc[tm][tn] = vzero;

    #pragma unroll
    for (int ks = 0; ks < 4; ++ks) {
      bf16x8 bh[2], bl[2], afh[4], afl[4];
      #pragma unroll
      for (int tn = 0; tn < 2; ++tn) {
        int g = nc * 8 + wv * 2 + tn;
        int widx = (g * 4 + ks) * 512 + ((quad << 4) + l15) * 8;
        bh[tn] = *(const bf16x8*)&W5h[widx];
        bl[tn] = *(const bf16x8*)&W5l[widx];
      }
      #pragma unroll
      for (int tm = 0; tm < 4; ++tm) {
        int off = (tm * 16 + l15) * 128 + (((ks * 4 + quad) ^ (l15 & 7)) << 3);
        afh[tm] = *(const bf16x8*)&Ah[off];
        afl[tm] = *(const bf16x8*)&Al[off];
      }
      #pragma unroll
      for (int tm = 0; tm < 4; ++tm)
        #pragma unroll
        for (int tn = 0; tn < 2; ++tn) {
          acc[tm][tn] = __builtin_amdgcn_mfma_f32_16x16x32_bf16(afh[tm], bh[tn], acc[tm][tn], 0, 0, 0);
          acc[tm][tn] = __builtin_amdgcn_mfma_f32_16x16x32_bf16(afh[tm], bl[tn], acc[tm][tn], 0, 0, 0);
          acc[tm][tn] = __builtin_amdgcn_mfma_f32_16x16x32_bf16(afl[tm], bh[tn], acc[tm][tn], 0, 0, 0);
        }
    }

    // argmax epilogue: in-thread pts ascend, so strict > keeps first index
    #pragma unroll
    for (int tn = 0; tn < 2; ++tn) {
      float rM = -3.4e38f; int rI = 0x7FFFFFFF;
      #pragma unroll
      for (int tm = 0; tm < 4; ++tm) {
        #pragma unroll
        for (int r = 0; r < 4; ++r) {
          int pt = mb + tm * 16 + (quad << 2) + r;
          float v = acc[tm][tn][r];
          if (pt < P && v > rM) { rM = v; rI = pt; }
        }
      }
      // fold across quads (lanes ^16, ^32), explicit first-index tie-break
      #pragma unroll
      for (int mk = 16; mk <= 32; mk <<= 1) {
        float v2 = __shfl_xor(rM, mk, 64);
        int   i2 = __shfl_xor(rI, mk, 64);
        if (v2 > rM || (v2 == rM && i2 < rI)) { rM = v2; rI = i2; }
      }
      if (quad == 0) {
        int ch = nc * 128 + wv * 32 + tn * 16 + l15;
        u64 key = ((u64)monoEnc(rM) << 32) | (unsigned)(8191 - (rI & 8191));
        atomicMax(&amax[b * 1024 + ch], key);
      }
    }
  }
}

// ---------------------------------------------------------------------------
// K3: decode packed per-channel argmax, BN sign test (z<=0 -> index 0),
// mark used bitmap, prefix-select first 600 unused indices (== stable
// ascending argsort of counts, k least-hit bins).
// ---------------------------------------------------------------------------
__global__ __launch_bounds__(256) void k3_select(
    const u64* __restrict__ amax,
    const float* __restrict__ g5, const float* __restrict__ b5,
    const float* __restrict__ m5, const float* __restrict__ v5,
    int* __restrict__ sel)
{
  __shared__ unsigned char used[8192];
  __shared__ int cnts[256];
  __shared__ int pref[256];
  const int b = blockIdx.x, tid = threadIdx.x;

  #pragma unroll
  for (int i = 0; i < 8; ++i) ((int*)used)[i * 256 + tid] = 0;
  __syncthreads();

  for (int ch = tid; ch < 1024; ch += 256) {
    u64 key = amax[b * 1024 + ch];
    float bm = monoDec((unsigned)(key >> 32));
    int   bi = 8191 - (int)(key & 0xFFFFFFFFu);
    float s5 = g5[ch] / sqrtf(v5[ch] + EPSBN);
    float z = fmaf(bm, s5, b5[ch] - m5[ch] * s5);
    int idx = (z > 0.f) ? (bi & 8191) : 0;
    used[idx] = 1;
  }
  __syncthreads();

  const int base = tid << 5;
  int c = 0;
  #pragma unroll
  for (int i = 0; i < 32; ++i) c += (used[base + i] == 0) ? 1 : 0;
  cnts[tid] = c;
  __syncthreads();
  if (tid == 0) {
    int r = 0;
    for (int i = 0; i < 256; ++i) { pref[i] = r; r += cnts[i]; }
  }
  __syncthreads();
  int rank = pref[tid];
  for (int i = 0; i < 32; ++i) {
    int n0 = base + i;
    if (!used[n0]) { if (rank < 600) sel[b * 600 + rank] = n0; ++rank; }
  }
}

// ---------------------------------------------------------------------------
// K6: pooled = relu(bn5(decode amax2)); fc1+bn6+relu; fc2 -> logits.
// ---------------------------------------------------------------------------
__global__ __launch_bounds__(512) void k6_fc(
    const u64* __restrict__ amax2,
    const float* __restrict__ g5, const float* __restrict__ b5,
    const float* __restrict__ m5, const float* __restrict__ v5,
    const float* __restrict__ L1w,
    const float* __restrict__ g6, const float* __restrict__ b6,
    const float* __restrict__ m6, const float* __restrict__ v6,
    const float* __restrict__ L2w, const float* __restrict__ L2b,
    float* __restrict__ out)
{
  __shared__ float pooled[1024];
  __shared__ float h6[512];
  const int b = blockIdx.x, tid = threadIdx.x;

  for (int ch = tid; ch < 1024; ch += 512) {
    float raw = monoDec((unsigned)(amax2[b * 1024 + ch] >> 32));
    float s5 = g5[ch] / sqrtf(v5[ch] + EPSBN);
    pooled[ch] = fmaxf(0.f, fmaf(raw, s5, b5[ch] - m5[ch] * s5));
  }
  __syncthreads();

  {
    const int o = tid;
    float a0 = 0.f, a1 = 0.f, a2 = 0.f, a3 = 0.f;
    for (int j = 0; j < 1024; j += 8) {
      float4 w0 = *(const float4*)&L1w[(size_t)o * 1024 + j];
      float4 w1 = *(const float4*)&L1w[(size_t)o * 1024 + j + 4];
      float4 p0 = *(const float4*)&pooled[j];
      float4 p1 = *(const float4*)&pooled[j + 4];
      a0 = fmaf(w0.x, p0.x, a0); a1 = fmaf(w0.y, p0.y, a1);
      a2 = fmaf(w0.z, p0.z, a2); a3 = fmaf(w0.w, p0.w, a3);
      a0 = fmaf(w1.x, p1.x, a0); a1 = fmaf(w1.y, p1.y, a1);
      a2 = fmaf(w1.z, p1.z, a2); a3 = fmaf(w1.w, p1.w, a3);
    }
    float acc = (a0 + a1) + (a2 + a3);
    float s6 = g6[o] / sqrtf(v6[o] + EPSBN);
    h6[o] = fmaxf(0.f, fmaf(acc, s6, b6[o] - m6[o] * s6));
  }
  __syncthreads();

  if (tid < 40) {
    float acc = L2b[tid];
    for (int j = 0; j < 512; j += 4) {
      float4 wv = *(const float4*)&L2w[(size_t)tid * 512 + j];
      acc = fmaf(wv.x, h6[j + 0], acc);
      acc = fmaf(wv.y, h6[j + 1], acc);
      acc = fmaf(wv.z, h6[j + 2], acc);
      acc = fmaf(wv.w, h6[j + 3], acc);
    }
    out[b * 40 + tid] = acc;
  }
}

// ---------------------------------------------------------------------------
// launcher
// ---------------------------------------------------------------------------
extern "C" void kernel_launch(void* const* d_in, const int* in_sizes, int n_in,
                              void* d_out, int out_size, void* d_ws, size_t ws_size,
                              hipStream_t stream)
{
  (void)in_sizes; (void)n_in; (void)out_size; (void)ws_size;
  const float* x   = (const float*)d_in[0];
  const float* W1  = (const float*)d_in[1];
  const float* g1  = (const float*)d_in[2];
  const float* b1  = (const float*)d_in[3];
  const float* m1  = (const float*)d_in[4];
  const float* v1  = (const float*)d_in[5];
  const float* W2  = (const float*)d_in[6];
  const float* g2  = (const float*)d_in[7];
  const float* b2  = (const float*)d_in[8];
  const float* m2  = (const float*)d_in[9];
  const float* v2  = (const float*)d_in[10];
  const float* W3  = (const float*)d_in[11];
  const float* g3  = (const float*)d_in[12];
  const float* b3  = (const float*)d_in[13];
  const float* m3  = (const float*)d_in[14];
  const float* v3  = (const float*)d_in[15];
  const float* W4  = (const float*)d_in[16];
  const float* g4  = (const float*)d_in[17];
  const float* b4  = (const float*)d_in[18];
  const float* m4  = (const float*)d_in[19];
  const float* v4  = (const float*)d_in[20];
  const float* W5  = (const float*)d_in[21];
  const float* g5  = (const float*)d_in[22];
  const float* b5  = (const float*)d_in[23];
  const float* m5  = (const float*)d_in[24];
  const float* v5  = (const float*)d_in[25];
  const float* L1w = (const float*)d_in[26];
  const float* g6  = (const float*)d_in[27];
  const float* b6  = (const float*)d_in[28];
  const float* m6  = (const float*)d_in[29];
  const float* v6  = (const float*)d_in[30];
  const float* L2w = (const float*)d_in[31];
  const float* L2b = (const float*)d_in[32];

  char* ws = (char*)d_ws;
  float* Wf    = (float*)(ws + 0);            // 68,864 B (pad to 69,632)
  u16*   W5h   = (u16*)(ws + 69632);          // 262,144 B
  u16*   W5l   = (u16*)(ws + 331776);         // 262,144 B
  u16*   H4a   = (u16*)(ws + 593920);         // 33,554,432 B
  u16*   H4b   = (u16*)(ws + 34148352);       // 33,554,432 B
  u64*   amax1 = (u64*)(ws + 67702784);       // 131,072 B
  u64*   amax2 = (u64*)(ws + 67833856);       // 131,072 B
  int*   sel   = (int*)(ws + 67964928);       // 38,400 B
  // total ~64.9 MB

  // zero-init both packed-argmax arrays (capture-legal async memset)
  hipMemsetAsync(ws + 67702784, 0, 262144, stream);

  k0_prep<<<578, 256, 0, stream>>>(W5, W1, W2, W3, W4,
                                   g1, b1, m1, v1, g2, b2, m2, v2,
                                   g3, b3, m3, v3, g4, b4, m4, v4,
                                   W5h, W5l, Wf);
  k1_conv<<<1024, 128, 0, stream>>>(x, Wf, H4a, H4b);
  k2_gemm<<<dim3(128, 16), 256, 0, stream>>>(H4a, H4b, W5h, W5l, nullptr,
                                             8192, amax1);
  k3_select<<<16, 256, 0, stream>>>(amax1, g5, b5, m5, v5, sel);
  k2_gemm<<<dim3(10, 16), 256, 0, stream>>>(H4a, H4b, W5h, W5l, sel,
                                            600, amax2);
  k6_fc<<<16, 512, 0, stream>>>(amax2, g5, b5, m5, v5, L1w,
                                g6, b6, m6, v6, L2w, L2b, (float*)d_out);
}

// Round 5
// 404.991 us; speedup vs baseline: 1.8207x; 1.8207x over previous
//
#include <hip/hip_runtime.h>
#include <cstdint>

typedef uint16_t u16;
typedef __attribute__((ext_vector_type(8))) short bf16x8;
typedef __attribute__((ext_vector_type(4))) float f32x4;

#define EPSBN 1e-5f

__device__ __forceinline__ float bf2f(u16 h) {
  return __uint_as_float(((unsigned)h) << 16);
}
__device__ __forceinline__ u16 f2bf(float f) {
  unsigned u = __float_as_uint(f);
  unsigned r = u + 0x7fffu + ((u >> 16) & 1u);
  return (u16)(r >> 16);
}

// ---------------------------------------------------------------------------
// K0: W5 -> bf16 hi/lo in FRAGMENT-LINEAR layout:
//   flat f: j=f&7, l15=(f>>3)&15, quad=(f>>7)&3, ks=(f>>9)&3, g=f>>11
//   holds W5[ch = g*16+l15][k = ks*32+quad*8+j]
//   => wave (lane = quad*16+l15) reads 1024 B contiguous per (g,ks).
// Also: transpose W2/W3/W4, copy W1, fold BN scale/shift for L1..L4 into Wf.
// Wf floats: Wt2@0(4096) Wt3@4096 Wt4@8192(8192) W1@16384(192)
//            scale@16576(320) shift@16896(320)
// ---------------------------------------------------------------------------
__global__ void k0_prep(const float* __restrict__ W5,
                        const float* __restrict__ W1, const float* __restrict__ W2,
                        const float* __restrict__ W3, const float* __restrict__ W4,
                        const float* g1, const float* b1, const float* m1, const float* v1,
                        const float* g2, const float* b2, const float* m2, const float* v2,
                        const float* g3, const float* b3, const float* m3, const float* v3,
                        const float* g4, const float* b4, const float* m4, const float* v4,
                        u16* __restrict__ W5h, u16* __restrict__ W5l,
                        float* __restrict__ Wf)
{
  int idx = blockIdx.x * 256 + threadIdx.x;
  if (idx < 131072) {
    int f = idx;
    int j = f & 7, l15 = (f >> 3) & 15, quad = (f >> 7) & 3, ks = (f >> 9) & 3, g = f >> 11;
    int ch = g * 16 + l15;
    int k  = ks * 32 + quad * 8 + j;
    float w = W5[ch * 128 + k];
    u16 hi = f2bf(w);
    W5h[f] = hi;
    W5l[f] = f2bf(w - bf2f(hi));
    return;
  }
  int j = idx - 131072;
  if (j < 4096) {                       // Wt2[j2*64+o] = W2[o*64+j2]
    Wf[j] = W2[(j & 63) * 64 + (j >> 6)];
  } else if (j < 8192) {
    int t = j - 4096;
    Wf[j] = W3[(t & 63) * 64 + (t >> 6)];
  } else if (j < 16384) {               // Wt4[j4*128+o] = W4[o*64+j4]
    int t = j - 8192;
    Wf[j] = W4[(t & 127) * 64 + (t >> 7)];
  } else if (j < 16576) {
    Wf[j] = W1[j - 16384];
  } else if (j < 16896) {
    int t = j - 16576;
    const float *g, *bb, *mm, *vv; int ch;
    if (t < 64)       { g = g1; bb = b1; mm = m1; vv = v1; ch = t;       }
    else if (t < 128) { g = g2; bb = b2; mm = m2; vv = v2; ch = t - 64;  }
    else if (t < 192) { g = g3; bb = b3; mm = m3; vv = v3; ch = t - 128; }
    else              { g = g4; bb = b4; mm = m4; vv = v4; ch = t - 192; }
    float s = g[ch] / sqrtf(vv[ch] + EPSBN);
    Wf[16576 + t] = s;
    Wf[16896 + t] = bb[ch] - mm[ch] * s;
  }
}

// ---------------------------------------------------------------------------
// K1: layers 1-4, one point per thread (unchanged from round 4).
// ---------------------------------------------------------------------------
__global__ __launch_bounds__(128, 2) void k1_conv(
    const float* __restrict__ x, const float* __restrict__ Wf,
    u16* __restrict__ H4a, u16* __restrict__ H4b)
{
  __shared__ float hs[64][128];
  const int tid = threadIdx.x;
  const int pid = blockIdx.x * 128 + tid;
  const int b = pid >> 13, n = pid & 8191;

  const float* __restrict__ Wt2 = Wf;
  const float* __restrict__ Wt3 = Wf + 4096;
  const float* __restrict__ Wt4 = Wf + 8192;
  const float* __restrict__ W1  = Wf + 16384;
  const float* __restrict__ SC  = Wf + 16576;
  const float* __restrict__ SH  = Wf + 16896;

  const float x0 = x[(b * 3 + 0) * 8192 + n];
  const float x1 = x[(b * 3 + 1) * 8192 + n];
  const float x2 = x[(b * 3 + 2) * 8192 + n];

  // L1 (3 -> 64)
  #pragma unroll
  for (int o = 0; o < 64; ++o) {
    float c = W1[o * 3] * x0;
    c = fmaf(W1[o * 3 + 1], x1, c);
    c = fmaf(W1[o * 3 + 2], x2, c);
    hs[o][tid] = fmaxf(0.f, fmaf(c, SC[o], SH[o]));
  }

  // L2 (64 -> 64)
  {
    float hn[64];
    #pragma unroll
    for (int o = 0; o < 64; ++o) hn[o] = 0.f;
    float hj = hs[0][tid];
    #pragma unroll 2
    for (int j = 0; j < 64; ++j) {
      float hjn = hs[(j + 1) & 63][tid];
      const float* __restrict__ wr = &Wt2[j * 64];
      #pragma unroll
      for (int o = 0; o < 64; ++o) hn[o] = fmaf(wr[o], hj, hn[o]);
      hj = hjn;
    }
    #pragma unroll
    for (int o = 0; o < 64; ++o)
      hs[o][tid] = fmaxf(0.f, fmaf(hn[o], SC[64 + o], SH[64 + o]));
  }

  // L3 (64 -> 64)
  {
    float hn[64];
    #pragma unroll
    for (int o = 0; o < 64; ++o) hn[o] = 0.f;
    float hj = hs[0][tid];
    #pragma unroll 2
    for (int j = 0; j < 64; ++j) {
      float hjn = hs[(j + 1) & 63][tid];
      const float* __restrict__ wr = &Wt3[j * 64];
      #pragma unroll
      for (int o = 0; o < 64; ++o) hn[o] = fmaf(wr[o], hj, hn[o]);
      hj = hjn;
    }
    #pragma unroll
    for (int o = 0; o < 64; ++o)
      hs[o][tid] = fmaxf(0.f, fmaf(hn[o], SC[128 + o], SH[128 + o]));
  }

  // L4 (64 -> 128) in 2 chunks of 64 outputs
  for (int half = 0; half < 2; ++half) {
    float hn[64];
    #pragma unroll
    for (int o = 0; o < 64; ++o) hn[o] = 0.f;
    float hj = hs[0][tid];
    #pragma unroll 2
    for (int j = 0; j < 64; ++j) {
      float hjn = hs[(j + 1) & 63][tid];
      const float* __restrict__ wr = &Wt4[j * 128 + half * 64];
      #pragma unroll
      for (int o = 0; o < 64; ++o) hn[o] = fmaf(wr[o], hj, hn[o]);
      hj = hjn;
    }
    #pragma unroll
    for (int o8 = 0; o8 < 8; ++o8) {
      int kg = half * 8 + o8;
      unsigned hv[4], lv[4];
      #pragma unroll
      for (int p = 0; p < 4; ++p) {
        int oc = o8 * 8 + 2 * p;
        float v0 = fmaxf(0.f, fmaf(hn[oc],     SC[192 + half * 64 + oc],     SH[192 + half * 64 + oc]));
        float v1 = fmaxf(0.f, fmaf(hn[oc + 1], SC[192 + half * 64 + oc + 1], SH[192 + half * 64 + oc + 1]));
        u16 a0 = f2bf(v0), a1 = f2bf(v1);
        float e0 = v0 - bf2f(a0), e1 = v1 - bf2f(a1);
        hv[p] = (unsigned)a0 | ((unsigned)a1 << 16);
        lv[p] = (unsigned)f2bf(e0) | ((unsigned)f2bf(e1) << 16);
      }
      uint4 ha, la;
      ha.x = hv[0]; ha.y = hv[1]; ha.z = hv[2]; ha.w = hv[3];
      la.x = lv[0]; la.y = lv[1]; la.z = lv[2]; la.w = lv[3];
      size_t e = ((size_t)(b * 16 + kg) * 8192 + n) * 8;
      *(uint4*)&H4a[e] = ha;
      *(uint4*)&H4b[e] = la;
    }
  }
}

// ---------------------------------------------------------------------------
// K2 v4: channel-stationary. grid (nc, ps, b). Block owns 256 channels:
// Bh frags hoisted to registers for the whole kernel (wave w -> ch
// [nc*256+w*64, +64)); Bl streamed per-tile from L2 (256 KB, always hot).
// Loops TPB point-tiles of 64 pts: stage Ah+Al (32 KB LDS, XOR swizzle),
// 192 MFMA/wave per tile (Ah*Bh + Ah*Bl + Al*Bh). Argmax carried in
// registers across ALL tiles; one quad-fold + plain partial store per block
// (pmax/pidx [b][ch][PS]) -- no atomics, no memset needed.
// ---------------------------------------------------------------------------
__global__ __launch_bounds__(256, 2) void k2_gemm(
    const u16* __restrict__ H4a, const u16* __restrict__ H4b,
    const u16* __restrict__ W5h, const u16* __restrict__ W5l,
    const int* __restrict__ sel,
    int P, int PS, int TPB,
    float* __restrict__ pmax, int* __restrict__ pidx)
{
  __shared__ u16 Ah[64 * 128];
  __shared__ u16 Al[64 * 128];

  const int nc = blockIdx.x;          // 256-channel group
  const int ps = blockIdx.y;          // point split
  const int b  = blockIdx.z;
  const int tid = threadIdx.x;
  const int lane = tid & 63, wv = tid >> 6;
  const int l15 = lane & 15, quad = lane >> 4;

  // hoist Bh fragments: 4 tn x 4 ks (64 VGPR), live for entire kernel
  bf16x8 bh[4][4];
  #pragma unroll
  for (int ks = 0; ks < 4; ++ks)
    #pragma unroll
    for (int tn = 0; tn < 4; ++tn) {
      int g = nc * 16 + wv * 4 + tn;
      bh[ks][tn] = *(const bf16x8*)&W5h[(size_t)(g * 4 + ks) * 512 + lane * 8];
    }

  float runM[4]; int runI[4];
  #pragma unroll
  for (int tn = 0; tn < 4; ++tn) { runM[tn] = -3.4e38f; runI[tn] = 0x7FFFFFFF; }

  const f32x4 vzero = {0.f, 0.f, 0.f, 0.f};

  for (int t = 0; t < TPB; ++t) {
    const int mb = (ps * TPB + t) << 6;
    if (mb >= P) break;               // uniform across block

    __syncthreads();                  // previous tile's LDS reads done
    // stage Ah+Al: iter i -> chunk c=i*4+wv, rows p=lane; chunk XOR-swizzled
    #pragma unroll
    for (int i = 0; i < 4; ++i) {
      int c = i * 4 + wv;
      int p = lane;
      int pt = mb + p;
      uint4 va; va.x = va.y = va.z = va.w = 0u;
      uint4 vb; vb.x = vb.y = vb.z = vb.w = 0u;
      int n0 = pt;
      bool ok = true;
      if (sel) { ok = (pt < P); n0 = ok ? (sel[b * 600 + pt] & 8191) : 0; }
      if (ok) {
        size_t e = ((size_t)(b * 16 + c) * 8192 + n0) * 8;
        va = *(const uint4*)&H4a[e];
        vb = *(const uint4*)&H4b[e];
      }
      int off = p * 128 + ((c ^ (p & 7)) << 3);
      *(uint4*)&Ah[off] = va;
      *(uint4*)&Al[off] = vb;
    }
    __syncthreads();

    f32x4 acc[4][4];
    #pragma unroll
    for (int tm = 0; tm < 4; ++tm)
      #pragma unroll
      for (int tn = 0; tn < 4; ++tn)
        acc[tm][tn] = vzero;

    #pragma unroll
    for (int ks = 0; ks < 4; ++ks) {
      bf16x8 bl[4], afh[4], afl[4];
      #pragma unroll
      for (int tn = 0; tn < 4; ++tn) {
        int g = nc * 16 + wv * 4 + tn;
        bl[tn] = *(const bf16x8*)&W5l[(size_t)(g * 4 + ks) * 512 + lane * 8];
      }
      #pragma unroll
      for (int tm = 0; tm < 4; ++tm) {
        int off = (tm * 16 + l15) * 128 + (((ks * 4 + quad) ^ (l15 & 7)) << 3);
        afh[tm] = *(const bf16x8*)&Ah[off];
        afl[tm] = *(const bf16x8*)&Al[off];
      }
      #pragma unroll
      for (int tm = 0; tm < 4; ++tm)
        #pragma unroll
        for (int tn = 0; tn < 4; ++tn) {
          acc[tm][tn] = __builtin_amdgcn_mfma_f32_16x16x32_bf16(afh[tm], bh[ks][tn], acc[tm][tn], 0, 0, 0);
          acc[tm][tn] = __builtin_amdgcn_mfma_f32_16x16x32_bf16(afh[tm], bl[tn],     acc[tm][tn], 0, 0, 0);
          acc[tm][tn] = __builtin_amdgcn_mfma_f32_16x16x32_bf16(afl[tm], bh[ks][tn], acc[tm][tn], 0, 0, 0);
        }
    }

    // fold this tile into the running argmax (pts ascend -> strict > keeps
    // first occurrence)
    #pragma unroll
    for (int tn = 0; tn < 4; ++tn) {
      #pragma unroll
      for (int tm = 0; tm < 4; ++tm) {
        #pragma unroll
        for (int r = 0; r < 4; ++r) {
          int pt = mb + tm * 16 + (quad << 2) + r;
          float v = acc[tm][tn][r];
          if (pt < P && v > runM[tn]) { runM[tn] = v; runI[tn] = pt; }
        }
      }
    }
  }

  // cross-quad fold (lanes ^16, ^32) + plain partial store
  #pragma unroll
  for (int tn = 0; tn < 4; ++tn) {
    float rM = runM[tn]; int rI = runI[tn];
    #pragma unroll
    for (int mk = 16; mk <= 32; mk <<= 1) {
      float v2 = __shfl_xor(rM, mk, 64);
      int   i2 = __shfl_xor(rI, mk, 64);
      if (v2 > rM || (v2 == rM && i2 < rI)) { rM = v2; rI = i2; }
    }
    if (quad == 0) {
      int ch = nc * 256 + wv * 64 + tn * 16 + l15;
      size_t o = ((size_t)b * 1024 + ch) * (size_t)PS + ps;
      pmax[o] = rM; pidx[o] = rI;
    }
  }
}

// ---------------------------------------------------------------------------
// K3: reduce PS=8 partials -> per-channel argmax (BN sign test), mark used
// bitmap, prefix-select first 600 unused indices (stable-argsort semantics).
// ---------------------------------------------------------------------------
__global__ __launch_bounds__(256) void k3_select(
    const float* __restrict__ pmax, const int* __restrict__ pidx,
    const float* __restrict__ g5, const float* __restrict__ b5,
    const float* __restrict__ m5, const float* __restrict__ v5,
    int* __restrict__ sel)
{
  __shared__ unsigned char used[8192];
  __shared__ int cnts[256];
  __shared__ int pref[256];
  const int b = blockIdx.x, tid = threadIdx.x;

  #pragma unroll
  for (int i = 0; i < 8; ++i) ((int*)used)[i * 256 + tid] = 0;
  __syncthreads();

  for (int ch = tid; ch < 1024; ch += 256) {
    const float* pm = pmax + (((size_t)b << 10) + ch) * 8;
    const int*   pi = pidx + (((size_t)b << 10) + ch) * 8;
    float bm = pm[0]; int bi = pi[0];
    #pragma unroll
    for (int s2 = 1; s2 < 8; ++s2) {
      float v = pm[s2]; int ii = pi[s2];
      if (v > bm || (v == bm && ii < bi)) { bm = v; bi = ii; }
    }
    float s5 = g5[ch] / sqrtf(v5[ch] + EPSBN);
    float z = fmaf(bm, s5, b5[ch] - m5[ch] * s5);
    int idx = (z > 0.f) ? (bi & 8191) : 0;   // all-nonpositive channel -> 0
    used[idx] = 1;
  }
  __syncthreads();

  const int base = tid << 5;
  int c = 0;
  #pragma unroll
  for (int i = 0; i < 32; ++i) c += (used[base + i] == 0) ? 1 : 0;
  cnts[tid] = c;
  __syncthreads();
  if (tid == 0) {
    int r = 0;
    for (int i = 0; i < 256; ++i) { pref[i] = r; r += cnts[i]; }
  }
  __syncthreads();
  int rank = pref[tid];
  for (int i = 0; i < 32; ++i) {
    int n0 = base + i;
    if (!used[n0]) { if (rank < 600) sel[b * 600 + rank] = n0; ++rank; }
  }
}

// ---------------------------------------------------------------------------
// K6: pooled = relu(bn5(max over 2 partials)); fc1+bn6+relu; fc2 -> logits.
// ---------------------------------------------------------------------------
__global__ __launch_bounds__(512) void k6_fc(
    const float* __restrict__ pmax2,
    const float* __restrict__ g5, const float* __restrict__ b5,
    const float* __restrict__ m5, const float* __restrict__ v5,
    const float* __restrict__ L1w,
    const float* __restrict__ g6, const float* __restrict__ b6,
    const float* __restrict__ m6, const float* __restrict__ v6,
    const float* __restrict__ L2w, const float* __restrict__ L2b,
    float* __restrict__ out)
{
  __shared__ float pooled[1024];
  __shared__ float h6[512];
  const int b = blockIdx.x, tid = threadIdx.x;

  for (int ch = tid; ch < 1024; ch += 512) {
    const float* pm = pmax2 + (((size_t)b << 10) + ch) * 2;
    float raw = fmaxf(pm[0], pm[1]);
    float s5 = g5[ch] / sqrtf(v5[ch] + EPSBN);
    pooled[ch] = fmaxf(0.f, fmaf(raw, s5, b5[ch] - m5[ch] * s5));
  }
  __syncthreads();

  {
    const int o = tid;
    float a0 = 0.f, a1 = 0.f, a2 = 0.f, a3 = 0.f;
    for (int j = 0; j < 1024; j += 8) {
      float4 w0 = *(const float4*)&L1w[(size_t)o * 1024 + j];
      float4 w1 = *(const float4*)&L1w[(size_t)o * 1024 + j + 4];
      float4 p0 = *(const float4*)&pooled[j];
      float4 p1 = *(const float4*)&pooled[j + 4];
      a0 = fmaf(w0.x, p0.x, a0); a1 = fmaf(w0.y, p0.y, a1);
      a2 = fmaf(w0.z, p0.z, a2); a3 = fmaf(w0.w, p0.w, a3);
      a0 = fmaf(w1.x, p1.x, a0); a1 = fmaf(w1.y, p1.y, a1);
      a2 = fmaf(w1.z, p1.z, a2); a3 = fmaf(w1.w, p1.w, a3);
    }
    float acc = (a0 + a1) + (a2 + a3);
    float s6 = g6[o] / sqrtf(v6[o] + EPSBN);
    h6[o] = fmaxf(0.f, fmaf(acc, s6, b6[o] - m6[o] * s6));
  }
  __syncthreads();

  if (tid < 40) {
    float acc = L2b[tid];
    for (int j = 0; j < 512; j += 4) {
      float4 wv = *(const float4*)&L2w[(size_t)tid * 512 + j];
      acc = fmaf(wv.x, h6[j + 0], acc);
      acc = fmaf(wv.y, h6[j + 1], acc);
      acc = fmaf(wv.z, h6[j + 2], acc);
      acc = fmaf(wv.w, h6[j + 3], acc);
    }
    out[b * 40 + tid] = acc;
  }
}

// ---------------------------------------------------------------------------
// launcher
// ---------------------------------------------------------------------------
extern "C" void kernel_launch(void* const* d_in, const int* in_sizes, int n_in,
                              void* d_out, int out_size, void* d_ws, size_t ws_size,
                              hipStream_t stream)
{
  (void)in_sizes; (void)n_in; (void)out_size; (void)ws_size;
  const float* x   = (const float*)d_in[0];
  const float* W1  = (const float*)d_in[1];
  const float* g1  = (const float*)d_in[2];
  const float* b1  = (const float*)d_in[3];
  const float* m1  = (const float*)d_in[4];
  const float* v1  = (const float*)d_in[5];
  const float* W2  = (const float*)d_in[6];
  const float* g2  = (const float*)d_in[7];
  const float* b2  = (const float*)d_in[8];
  const float* m2  = (const float*)d_in[9];
  const float* v2  = (const float*)d_in[10];
  const float* W3  = (const float*)d_in[11];
  const float* g3  = (const float*)d_in[12];
  const float* b3  = (const float*)d_in[13];
  const float* m3  = (const float*)d_in[14];
  const float* v3  = (const float*)d_in[15];
  const float* W4  = (const float*)d_in[16];
  const float* g4  = (const float*)d_in[17];
  const float* b4  = (const float*)d_in[18];
  const float* m4  = (const float*)d_in[19];
  const float* v4  = (const float*)d_in[20];
  const float* W5  = (const float*)d_in[21];
  const float* g5  = (const float*)d_in[22];
  const float* b5  = (const float*)d_in[23];
  const float* m5  = (const float*)d_in[24];
  const float* v5  = (const float*)d_in[25];
  const float* L1w = (const float*)d_in[26];
  const float* g6  = (const float*)d_in[27];
  const float* b6  = (const float*)d_in[28];
  const float* m6  = (const float*)d_in[29];
  const float* v6  = (const float*)d_in[30];
  const float* L2w = (const float*)d_in[31];
  const float* L2b = (const float*)d_in[32];

  char* ws = (char*)d_ws;
  float* Wf    = (float*)(ws + 0);            // 68,864 B (pad to 69,632)
  u16*   W5h   = (u16*)(ws + 69632);          // 262,144 B
  u16*   W5l   = (u16*)(ws + 331776);         // 262,144 B
  u16*   H4a   = (u16*)(ws + 593920);         // 33,554,432 B
  u16*   H4b   = (u16*)(ws + 34148352);       // 33,554,432 B
  float* pmax  = (float*)(ws + 67702784);     // 524,288 B  (16*1024*8)
  int*   pidx  = (int*)(ws + 68227072);       // 524,288 B
  float* pmax2 = (float*)(ws + 68751360);     // 131,072 B  (16*1024*2)
  int*   pidx2 = (int*)(ws + 68882432);       // 131,072 B
  int*   sel   = (int*)(ws + 69013504);       // 38,400 B
  // total ~65.9 MB

  k0_prep<<<578, 256, 0, stream>>>(W5, W1, W2, W3, W4,
                                   g1, b1, m1, v1, g2, b2, m2, v2,
                                   g3, b3, m3, v3, g4, b4, m4, v4,
                                   W5h, W5l, Wf);
  k1_conv<<<1024, 128, 0, stream>>>(x, Wf, H4a, H4b);
  k2_gemm<<<dim3(4, 8, 16), 256, 0, stream>>>(H4a, H4b, W5h, W5l, nullptr,
                                              8192, 8, 16, pmax, pidx);
  k3_select<<<16, 256, 0, stream>>>(pmax, pidx, g5, b5, m5, v5, sel);
  k2_gemm<<<dim3(4, 2, 16), 256, 0, stream>>>(H4a, H4b, W5h, W5l, sel,
                                              600, 2, 5, pmax2, pidx2);
  k6_fc<<<16, 512, 0, stream>>>(pmax2, g5, b5, m5, v5, L1w,
                                g6, b6, m6, v6, L2w, L2b, (float*)d_out);
}